// Round 11
// baseline (367.708 us; speedup 1.0000x reference)
//
#include <hip/hip_runtime.h>

typedef unsigned short u16;
typedef __attribute__((ext_vector_type(8))) short bf16x8;
typedef __attribute__((ext_vector_type(4))) float f32x4;
typedef __attribute__((ext_vector_type(4))) u16 u16x4;
typedef __attribute__((ext_vector_type(8))) u16 u16x8;

#define MFMA16(a, b, c) __builtin_amdgcn_mfma_f32_16x16x32_bf16(a, b, c, 0, 0, 0)

__device__ __forceinline__ u16 f2bf(float f) {
    union { float f; unsigned u; } v; v.f = f;
    unsigned r = (v.u + 0x7FFFu + ((v.u >> 16) & 1u)) >> 16;  // RNE
    return (u16)r;
}

__device__ __forceinline__ void gload_lds16(const void* g, void* l) {
    __builtin_amdgcn_global_load_lds((const __attribute__((address_space(1))) void*)g,
                                     (__attribute__((address_space(3))) void*)l, 16, 0, 0);
}

// ---------- prep: fp32 -> bf16 (optionally scaled) ----------
__global__ __launch_bounds__(256) void cvt_kernel(const float* __restrict__ src,
                                                  u16* __restrict__ dst, int n4, float scale) {
    int i = blockIdx.x * 256 + threadIdx.x;
    if (i >= n4) return;
    f32x4 v = *(const f32x4*)(src + (size_t)i * 4);
    u16x4 o;
#pragma unroll
    for (int j = 0; j < 4; ++j) o[j] = f2bf(v[j] * scale);
    *(u16x4*)(dst + (size_t)i * 4) = o;
}

// ---------- prep: V (8192x512 f32) -> Vt (512x8192 bf16) ----------
__global__ __launch_bounds__(256) void prep_vt(const float* __restrict__ V, u16* __restrict__ Vt) {
    __shared__ float tile[64][65];
    int t = threadIdx.x;
    int n0 = blockIdx.x * 64;
    int d0 = blockIdx.y * 64;
    int tr = t >> 4, tc = t & 15;
#pragma unroll
    for (int p = 0; p < 4; ++p) {
        int n = p * 16 + tr;
        f32x4 v = *(const f32x4*)(V + (size_t)(n0 + n) * 512 + d0 + tc * 4);
#pragma unroll
        for (int j = 0; j < 4; ++j) tile[n][tc * 4 + j] = v[j];
    }
    __syncthreads();
#pragma unroll
    for (int p = 0; p < 4; ++p) {
        int d = p * 16 + tr;
        u16x4 o;
#pragma unroll
        for (int j = 0; j < 4; ++j) o[j] = f2bf(tile[tc * 4 + j][d]);
        *(u16x4*)(Vt + (size_t)(d0 + d) * 8192 + n0 + tc * 4) = o;
    }
}

__global__ __launch_bounds__(256) void zero_kernel(float* __restrict__ p, int n) {
    int i = blockIdx.x * 256 + threadIdx.x;
    if (i < n) p[i] = 0.f;
}

// ================= GEMM1: P = exp(Qs . Kb^T), l[row] += rowsum ==================
// 4096 blocks (XCD-grouped), 256 thr / 4 waves, tile 128x128, wave 64x64, BK=64 dbuf.
__global__ __launch_bounds__(256) void gemm1_kernel(const u16* __restrict__ Qs,
                                                    const u16* __restrict__ Kb,
                                                    u16* __restrict__ P,
                                                    float* __restrict__ l) {
    __shared__ __align__(16) u16 smem[32768];  // A dbuf @0/8192, B dbuf @16384/24576 (64 KB)
    const int tid = threadIdx.x;
    const int wid = tid >> 6;
    const int lane = tid & 63;
    const int lo = lane & 15;
    const int hi = lane >> 4;
    const int wr = wid >> 1, wc = wid & 1;
    const int subrow = lane >> 3, ch = lane & 7;

    // XCD x owns keys [x*1024, +1024): 8 bn-panels; consecutive g share the Qs bm-panel
    const int bid = blockIdx.x;
    const int x = bid & 7, g = bid >> 3;
    const int m0 = (g >> 3) * 128;
    const int n0 = (x * 8 + (g & 7)) * 128;

    const u16* Abase = Qs + (size_t)m0 * 512;
    const u16* Bbase = Kb + (size_t)n0 * 512;
    const int src_off = subrow * 512 + ((ch ^ subrow) << 3);  // 8-row chunk, pre-swizzled src

#define G1_STAGE(KS, BUF)                                                              \
    {                                                                                  \
        u16* la_ = smem + (BUF) * 8192;                                                \
        u16* lb_ = smem + 16384 + (BUF) * 8192;                                        \
        _Pragma("unroll") for (int i_ = 0; i_ < 4; ++i_) {                             \
            int rb_ = wid * 32 + i_ * 8;                                               \
            gload_lds16(Abase + (size_t)rb_ * 512 + (KS) * 64 + src_off, la_ + rb_ * 64); \
            gload_lds16(Bbase + (size_t)rb_ * 512 + (KS) * 64 + src_off, lb_ + rb_ * 64); \
        }                                                                              \
    }

    f32x4 acc[4][4];
#pragma unroll
    for (int a = 0; a < 4; ++a)
#pragma unroll
        for (int b = 0; b < 4; ++b) acc[a][b] = (f32x4){0.f, 0.f, 0.f, 0.f};

    G1_STAGE(0, 0)
    asm volatile("s_waitcnt vmcnt(0)\n\ts_barrier" ::: "memory");

#pragma unroll
    for (int s = 0; s < 8; ++s) {
        const int cur = s & 1;
        if (s < 7) G1_STAGE(s + 1, cur ^ 1)
        const u16* la = smem + cur * 8192;
        const u16* lb = smem + 16384 + cur * 8192;
        __builtin_amdgcn_s_setprio(1);
#pragma unroll
        for (int kk = 0; kk < 2; ++kk) {
            bf16x8 af[4], bf[4];
#pragma unroll
            for (int mt = 0; mt < 4; ++mt) {
                int r = wr * 64 + mt * 16 + lo;
                af[mt] = *(const bf16x8*)(la + r * 64 + (((kk * 4 + hi) ^ (r & 7)) << 3));
            }
#pragma unroll
            for (int nt = 0; nt < 4; ++nt) {
                int r = wc * 64 + nt * 16 + lo;
                bf[nt] = *(const bf16x8*)(lb + r * 64 + (((kk * 4 + hi) ^ (r & 7)) << 3));
            }
#pragma unroll
            for (int mt = 0; mt < 4; ++mt)
#pragma unroll
                for (int nt = 0; nt < 4; ++nt)
                    acc[mt][nt] = MFMA16(af[mt], bf[nt], acc[mt][nt]);
        }
        __builtin_amdgcn_s_setprio(0);
        asm volatile("s_waitcnt vmcnt(0) lgkmcnt(0)\n\ts_barrier" ::: "memory");
    }

    // ---- epilogue: exp in place; row-sums -> atomicAdd l; LDS bounce -> coalesced P ----
#pragma unroll
    for (int mt = 0; mt < 4; ++mt)
#pragma unroll
        for (int nt = 0; nt < 4; ++nt)
#pragma unroll
            for (int r = 0; r < 4; ++r) acc[mt][nt][r] = __expf(acc[mt][nt][r]);

#pragma unroll
    for (int mt = 0; mt < 4; ++mt)
#pragma unroll
        for (int r = 0; r < 4; ++r) {
            float rs = acc[mt][0][r] + acc[mt][1][r] + acc[mt][2][r] + acc[mt][3][r];
            rs += __shfl_xor(rs, 1);
            rs += __shfl_xor(rs, 2);
            rs += __shfl_xor(rs, 4);
            rs += __shfl_xor(rs, 8);
            if (lo == 0) atomicAdd(&l[m0 + wr * 64 + mt * 16 + 4 * hi + r], rs);
        }

    __syncthreads();  // K-loop LDS dead; MFMAs retired
#pragma unroll
    for (int mt = 0; mt < 4; ++mt)
#pragma unroll
        for (int nt = 0; nt < 4; ++nt)
#pragma unroll
            for (int r = 0; r < 4; ++r) {
                int row = wr * 64 + mt * 16 + 4 * hi + r;
                int col = wc * 64 + nt * 16 + lo;
                int c16 = col >> 3;
                int sw = (c16 & 8) | ((c16 ^ row) & 7);
                smem[row * 128 + sw * 8 + (col & 7)] = f2bf(acc[mt][nt][r]);
            }
    __syncthreads();
    {
        int row = tid >> 1, half = tid & 1;
        u16* dst = P + (size_t)(m0 + row) * 8192 + n0 + half * 64;
#pragma unroll
        for (int c = 0; c < 8; ++c) {
            int c16 = half * 8 + c;
            int sw = (c16 & 8) | ((c16 ^ row) & 7);
            *(u16x8*)(dst + c * 8) = *(const u16x8*)(smem + row * 128 + sw * 8);
        }
    }
#undef G1_STAGE
}

// ================= GEMM2: out = (P . V) / l ==================
// 256 blocks (bm 64 x bn 4, XCD owns one bn => Vt panel 2MB L2-resident), 512 thr / 8 waves,
// tile 128x128, wave 64x32; A=P staged dbuf (32KB), B=Vt direct from global; 128 steps.
__global__ __launch_bounds__(512) void gemm2_kernel(const u16* __restrict__ P,
                                                    const u16* __restrict__ Vt,
                                                    const float* __restrict__ l,
                                                    float* __restrict__ out) {
    __shared__ __align__(16) u16 smem[16384];  // A dbuf 2 x (128x64)
    const int tid = threadIdx.x;
    const int wid = tid >> 6;
    const int lane = tid & 63;
    const int lo = lane & 15;
    const int hi = lane >> 4;
    const int wr = wid >> 2, wc = wid & 3;
    const int subrow = lane >> 3, ch = lane & 7;

    const int bid = blockIdx.x;
    const int x = bid & 7, g = bid >> 3;   // 256 % 8 == 0 -> bijective
    const int bn = x & 3;
    const int bm = (g << 1) + (x >> 2);
    const int m0 = bm * 128, n0 = bn * 128;

    const u16* Abase = P + (size_t)m0 * 8192;
    const int src_off = subrow * 8192 + ((ch ^ subrow) << 3);

#define G2_STAGE(KS, BUF)                                                                 \
    {                                                                                     \
        u16* la_ = smem + (BUF) * 8192;                                                   \
        _Pragma("unroll") for (int i_ = 0; i_ < 2; ++i_) {                                \
            int rb_ = wid * 16 + i_ * 8;                                                  \
            gload_lds16(Abase + (size_t)rb_ * 8192 + (size_t)(KS) * 64 + src_off,         \
                        la_ + rb_ * 64);                                                  \
        }                                                                                 \
    }

    f32x4 acc[4][2];
#pragma unroll
    for (int a = 0; a < 4; ++a)
#pragma unroll
        for (int b = 0; b < 2; ++b) acc[a][b] = (f32x4){0.f, 0.f, 0.f, 0.f};

    G2_STAGE(0, 0)
    asm volatile("s_waitcnt vmcnt(0)\n\ts_barrier" ::: "memory");

    const u16* vbase = Vt + (size_t)(n0 + wc * 32 + lo) * 8192;

    for (int s = 0; s < 128; ++s) {
        const int cur = s & 1;
        if (s < 127) G2_STAGE(s + 1, cur ^ 1)
        bf16x8 vb[2][2];
#pragma unroll
        for (int nt = 0; nt < 2; ++nt)
#pragma unroll
            for (int kk = 0; kk < 2; ++kk)
                vb[nt][kk] = *(const bf16x8*)(vbase + (size_t)nt * 16 * 8192 +
                                              s * 64 + kk * 32 + hi * 8);
        const u16* la = smem + cur * 8192;
        __builtin_amdgcn_s_setprio(1);
#pragma unroll
        for (int kk = 0; kk < 2; ++kk) {
            bf16x8 af[4];
#pragma unroll
            for (int mt = 0; mt < 4; ++mt) {
                int r = wr * 64 + mt * 16 + lo;
                af[mt] = *(const bf16x8*)(la + r * 64 + (((kk * 4 + hi) ^ (r & 7)) << 3));
            }
#pragma unroll
            for (int mt = 0; mt < 4; ++mt)
#pragma unroll
                for (int nt = 0; nt < 2; ++nt)
                    acc[mt][nt] = MFMA16(af[mt], vb[nt][kk], acc[mt][nt]);
        }
        __builtin_amdgcn_s_setprio(0);
        asm volatile("s_waitcnt vmcnt(0) lgkmcnt(0)\n\ts_barrier" ::: "memory");
    }

    // ---- epilogue: scale by 1/l[row], write f32 out ----
#pragma unroll
    for (int mt = 0; mt < 4; ++mt)
#pragma unroll
        for (int r = 0; r < 4; ++r) {
            int row = m0 + wr * 64 + mt * 16 + 4 * hi + r;
            float inv = 1.0f / l[row];
            float* orow = out + (size_t)row * 512 + n0 + wc * 32 + lo;
            orow[0] = acc[mt][0][r] * inv;
            orow[16] = acc[mt][1][r] * inv;
        }
#undef G2_STAGE
}

// ===================== fallback path (R10 flash, proven) =====================
__global__ __launch_bounds__(512) void flash_kernel(
    const u16* __restrict__ Qs, const u16* __restrict__ Kb, const u16* __restrict__ Vt,
    float* __restrict__ Opart, float* __restrict__ lpart) {
    __shared__ __align__(16) u16 lds_k[2][64 * 512];
    __shared__ __align__(16) u16 lds_p[2][64 * 64];
    __shared__ float s_l[2][64];

    const int tid = threadIdx.x;
    const int wid = tid >> 6;
    const int lane = tid & 63;
    const int lo = lane & 15;
    const int hi = lane >> 4;
    const int mi = wid >> 1;
    const int nj = wid & 1;

    const int bx = blockIdx.x;
    const int x = bx & 7;
    const int g = bx >> 3;
    const int ks = x >> 2;
    const int mtile = g * 4 + (x & 3);
    const int key0 = ks * 4096;

    bf16x8 qf[16];
    {
        const u16* qrow = Qs + (size_t)(mtile * 64 + mi * 16 + lo) * 512 + hi * 8;
#pragma unroll
        for (int kt = 0; kt < 16; ++kt) qf[kt] = *(const bf16x8*)(qrow + kt * 32);
    }

    f32x4 o[4][4];
#pragma unroll
    for (int a = 0; a < 4; ++a)
#pragma unroll
        for (int b = 0; b < 4; ++b) o[a][b] = (f32x4){0.f, 0.f, 0.f, 0.f};
    float lsum = 0.f;
    bf16x8 vb[4][2];

    const int cbase = ((hi ^ (lo & 3)) + ((lo >> 2) & 1) * 4) * 8;
    const int rowA = (nj * 32 + lo) * 512;

    const int qrow = mi * 16 + lo;
    const int ch0 = ((nj * 4 + (hi >> 1)) ^ (qrow & 7));
    const int ch1 = ((nj * 4 + 2 + (hi >> 1)) ^ (qrow & 7));
    const int pw0 = qrow * 64 + (ch0 << 3) + (hi & 1) * 4;
    const int pw1 = qrow * 64 + (ch1 << 3) + (hi & 1) * 4;

#define STAGE_K(IT, BUF)                                                            \
    {                                                                               \
        const u16* kb_ = Kb + (size_t)(key0 + (IT) * 64) * 512;                     \
        _Pragma("unroll") for (int r8_ = 0; r8_ < 8; ++r8_) {                       \
            int row_ = (wid << 3) + r8_;                                            \
            gload_lds16(kb_ + (size_t)row_ * 512 + ((lane ^ (row_ & 7)) << 3),      \
                        &lds_k[BUF][row_ * 512]);                                   \
        }                                                                           \
    }
#define S_COMPUTE(BUF, S0A, S0B, S1A, S1B)                                          \
    {                                                                               \
        const u16* kb = &lds_k[BUF][0];                                             \
        const u16* pAe = kb + rowA + cbase;                                         \
        const u16* pAo = kb + rowA + (cbase ^ 32);                                  \
        const u16* pBe = pAe + 16 * 512;                                            \
        const u16* pBo = pAo + 16 * 512;                                            \
        _Pragma("unroll") for (int kt2 = 0; kt2 < 8; ++kt2) {                       \
            bf16x8 ae = *(const bf16x8*)(pAe + kt2 * 64);                           \
            bf16x8 be = *(const bf16x8*)(pBe + kt2 * 64);                           \
            bf16x8 ao = *(const bf16x8*)(pAo + kt2 * 64);                           \
            bf16x8 bo = *(const bf16x8*)(pBo + kt2 * 64);                           \
            S0A = MFMA16(ae, qf[2 * kt2], S0A);                                     \
            S1A = MFMA16(be, qf[2 * kt2], S1A);                                     \
            S0B = MFMA16(ao, qf[2 * kt2 + 1], S0B);                                 \
            S1B = MFMA16(bo, qf[2 * kt2 + 1], S1B);                                 \
        }                                                                           \
    }
#define PV_STEP(PBUF)                                                               \
    {                                                                               \
        _Pragma("unroll") for (int mt = 0; mt < 4; ++mt) {                          \
            int m = mt * 16 + lo;                                                   \
            int c0 = hi ^ (m & 7);                                                  \
            int c1 = (4 + hi) ^ (m & 7);                                            \
            bf16x8 pa0 = *(const bf16x8*)(&lds_p[PBUF][m * 64 + c0 * 8]);           \
            bf16x8 pa1 = *(const bf16x8*)(&lds_p[PBUF][m * 64 + c1 * 8]);           \
            _Pragma("unroll") for (int nt = 0; nt < 4; ++nt) {                      \
                f32x4 c_ = o[mt][nt];                                               \
                c_ = MFMA16(pa0, vb[nt][0], c_);                                    \
                c_ = MFMA16(pa1, vb[nt][1], c_);                                    \
                o[mt][nt] = c_;                                                     \
            }                                                                       \
        }                                                                           \
    }
#define EXP_PW(S0, S1, PBUF)                                                        \
    {                                                                               \
        u16x4 w0, w1;                                                               \
        _Pragma("unroll") for (int r = 0; r < 4; ++r) {                             \
            float p0 = __expf((S0)[r]);                                             \
            float p1 = __expf((S1)[r]);                                             \
            lsum += p0 + p1;                                                        \
            w0[r] = f2bf(p0);                                                       \
            w1[r] = f2bf(p1);                                                       \
        }                                                                           \
        *(u16x4*)(&lds_p[PBUF][pw0]) = w0;                                          \
        *(u16x4*)(&lds_p[PBUF][pw1]) = w1;                                          \
    }
#define VB_LOAD(T)                                                                  \
    {                                                                               \
        _Pragma("unroll") for (int nt = 0; nt < 4; ++nt) {                          \
            const u16* vrow = Vt + (size_t)(wid * 64 + nt * 16 + lo) * 8192 +       \
                              key0 + (T) * 64 + hi * 8;                             \
            vb[nt][0] = *(const bf16x8*)(vrow);                                     \
            vb[nt][1] = *(const bf16x8*)(vrow + 32);                                \
        }                                                                           \
    }

    STAGE_K(0, 0)
    asm volatile("s_waitcnt vmcnt(0)\n\ts_barrier" ::: "memory");
    {
        STAGE_K(1, 1)
        f32x4 s0a = {0.f, 0.f, 0.f, 0.f}, s0b = s0a, s1a = s0a, s1b = s0a;
        VB_LOAD(0)
        __builtin_amdgcn_s_setprio(1);
        S_COMPUTE(0, s0a, s0b, s1a, s1b)
        __builtin_amdgcn_s_setprio(0);
        f32x4 s0 = s0a + s0b, s1 = s1a + s1b;
        EXP_PW(s0, s1, 0)
        asm volatile("s_waitcnt vmcnt(0) lgkmcnt(0)\n\ts_barrier" ::: "memory");
    }
    for (int t = 1; t < 64; ++t) {
        const int cur = t & 1;
        if (t < 63) STAGE_K(t + 1, cur ^ 1)
        __builtin_amdgcn_s_setprio(1);
        PV_STEP(cur ^ 1)
        __builtin_amdgcn_s_setprio(0);
        VB_LOAD(t)
        f32x4 s0a = {0.f, 0.f, 0.f, 0.f}, s0b = s0a, s1a = s0a, s1b = s0a;
        __builtin_amdgcn_s_setprio(1);
        S_COMPUTE(cur, s0a, s0b, s1a, s1b)
        __builtin_amdgcn_s_setprio(0);
        f32x4 s0 = s0a + s0b, s1 = s1a + s1b;
        EXP_PW(s0, s1, cur)
        asm volatile("s_waitcnt vmcnt(0) lgkmcnt(0)\n\ts_barrier" ::: "memory");
    }
    __builtin_amdgcn_s_setprio(1);
    PV_STEP(1)
    __builtin_amdgcn_s_setprio(0);

    lsum += __shfl_xor(lsum, 16);
    lsum += __shfl_xor(lsum, 32);
    if (lane < 16) s_l[nj][qrow] = lsum;
    __syncthreads();

    const int lb = mtile * 2 + ks;
    {
        float* Ob = Opart + (size_t)lb * (64 * 512);
#pragma unroll
        for (int mt = 0; mt < 4; ++mt)
#pragma unroll
            for (int nt = 0; nt < 4; ++nt)
#pragma unroll
                for (int r = 0; r < 4; ++r) {
                    int row = mt * 16 + hi * 4 + r;
                    int col = wid * 64 + nt * 16 + lo;
                    Ob[row * 512 + col] = o[mt][nt][r];
                }
        if (tid < 64) lpart[lb * 64 + tid] = s_l[0][tid] + s_l[1][tid];
    }
}

__global__ __launch_bounds__(256) void combine_kernel(const float* __restrict__ Opart,
                                                      const float* __restrict__ lpart,
                                                      float* __restrict__ out) {
    int i = blockIdx.x * 256 + threadIdx.x;
    int row = i >> 7;
    int c4 = i & 127;
    int mtile = row >> 6, rl = row & 63;
    int b0 = mtile * 2, b1 = b0 + 1;
    float inv = 1.0f / (lpart[b0 * 64 + rl] + lpart[b1 * 64 + rl]);
    f32x4 a = *(const f32x4*)(Opart + (size_t)b0 * 32768 + rl * 512 + c4 * 4);
    f32x4 b = *(const f32x4*)(Opart + (size_t)b1 * 32768 + rl * 512 + c4 * 4);
    f32x4 r = (a + b) * inv;
    *(f32x4*)(out + (size_t)row * 512 + c4 * 4) = r;
}

extern "C" void kernel_launch(void* const* d_in, const int* in_sizes, int n_in,
                              void* d_out, int out_size, void* d_ws, size_t ws_size,
                              hipStream_t stream) {
    const float* Q = (const float*)d_in[0];
    const float* K = (const float*)d_in[1];
    const float* V = (const float*)d_in[2];
    float* out = (float*)d_out;
    char* ws = (char*)d_ws;

    const float scale = 0.08838834764831845f;  // 2/sqrt(512): softmax(s)^2 renorm == softmax(2s)

    // common prep buffers
    u16* Qs = (u16*)(ws + 0);
    u16* Kb = (u16*)(ws + 8388608);
    u16* Vt = (u16*)(ws + 16777216);

    cvt_kernel<<<4096, 256, 0, stream>>>(Q, Qs, 1048576, scale);
    cvt_kernel<<<4096, 256, 0, stream>>>(K, Kb, 1048576, 1.0f);
    prep_vt<<<dim3(128, 8), 256, 0, stream>>>(V, Vt);

    const size_t need = 25165824ull + 65536ull + 134217728ull;  // + l + P
    if (ws_size >= need) {
        float* lsum = (float*)(ws + 25165824);
        u16* P = (u16*)(ws + 25165824 + 65536);
        zero_kernel<<<32, 256, 0, stream>>>(lsum, 8192);
        gemm1_kernel<<<4096, 256, 0, stream>>>(Qs, Kb, P, lsum);
        gemm2_kernel<<<256, 512, 0, stream>>>(P, Vt, lsum, out);
    } else {
        float* Op = (float*)(ws + 25165824);
        float* lp = (float*)(ws + 58720256);
        flash_kernel<<<256, 512, 0, stream>>>(Qs, Kb, Vt, Op, lp);
        combine_kernel<<<4096, 256, 0, stream>>>(Op, lp, out);
    }
}